// Round 7
// baseline (2848.175 us; speedup 1.0000x reference)
//
#include <hip/hip_runtime.h>
#include <hip/hip_bf16.h>

// DelayRNN on MI355X — Round 7.
// (1) Staging merged into GEMM: h0 published as per-WG 1KB slices
//     [32 rows][16 cols]; consumers load MFMA A-frags DIRECTLY from slice
//     buffers via one 32-load sc0/sc1 asm batch (single drain). Detect = 32
//     per-WG flags polled in parallel (1 RTT). No LDS h0 stage, one fewer
//     barrier, one fewer RTT in the serial chain.
// (2) Clock-floor attack: grid padded to 256 WGs; WGs 32..255 run dense FMA
//     spin (poll `done`) to force the DPM governor to high SCLK — testing the
//     idle-throttle hypothesis for the ~7us/step floor.

constexpr int kB    = 32;
constexpr int kS    = 256;
constexpr int kI    = 128;
constexpr int kH    = 512;
constexpr int kC    = 64;
constexpr int kOutL = 64;
constexpr int kMaxD = 16;
constexpr int kBufD = 17;
constexpr int kNWG  = 32;    // real (recurrence) workgroups
constexpr int kGrid = 256;   // real + clock-boost dummies
constexpr int kJPW  = 16;
constexpr int kSteps = kS + kOutL;   // 320
constexpr int kKz   = kH + kI;       // 640

typedef __bf16 bf16x8 __attribute__((ext_vector_type(8)));
typedef float  f32x4  __attribute__((ext_vector_type(4)));
typedef unsigned int u32x4 __attribute__((ext_vector_type(4)));

__device__ __forceinline__ f32x4 MFMA(bf16x8 a, bf16x8 b, f32x4 c) {
  return __builtin_amdgcn_mfma_f32_16x16x32_bf16(a, b, c, 0, 0, 0);
}
__device__ __forceinline__ bf16x8 ld8(const __hip_bfloat16* p) {
  return *reinterpret_cast<const bf16x8*>(p);
}
__device__ __forceinline__ bf16x8 asbf(u32x4 x) {
  union { u32x4 u; bf16x8 v; } c; c.u = x; return c.v;
}
__device__ __forceinline__ bf16x8 ld8_f32(const float* p) {
  float4 a = *(const float4*)p, b = *(const float4*)(p + 4);
  union { __hip_bfloat16 h[8]; bf16x8 v; } c;
  c.h[0] = __float2bfloat16(a.x); c.h[1] = __float2bfloat16(a.y);
  c.h[2] = __float2bfloat16(a.z); c.h[3] = __float2bfloat16(a.w);
  c.h[4] = __float2bfloat16(b.x); c.h[5] = __float2bfloat16(b.y);
  c.h[6] = __float2bfloat16(b.z); c.h[7] = __float2bfloat16(b.w);
  return c.v;
}
__device__ __forceinline__ float sigm(float x) { return 1.0f / (1.0f + __expf(-x)); }

// ---------------- prep kernels (unchanged) ----------------

__global__ void prep_cast(const float* x, const float* W_in, const float* W_pass,
                          const float* W_tau, const float* W_mem, const float* W_out,
                          __hip_bfloat16* xb, __hip_bfloat16* Wall, __hip_bfloat16* BtP,
                          __hip_bfloat16* BtT, __hip_bfloat16* BtM, __hip_bfloat16* WtOut) {
  const int tid = blockIdx.x * blockDim.x + threadIdx.x;
  const int nth = gridDim.x * blockDim.x;
  for (int i = tid; i < kB * kS * kI; i += nth) xb[i] = __float2bfloat16(x[i]);
  for (int i = tid; i < kH * kKz; i += nth) {
    int j = i / kKz, k = i - j * kKz;
    Wall[i] = __float2bfloat16(W_in[k * kH + j]);
  }
  for (int i = tid; i < kH * kH; i += nth) {
    int j = i >> 9, k = i & 511;
    BtP[i] = __float2bfloat16(W_pass[k * kH + j]);
    BtT[i] = __float2bfloat16(W_tau[k * kH + j]);
    BtM[i] = __float2bfloat16(W_mem[k * kH + j]);
  }
  for (int i = tid; i < kC * kH; i += nth) {
    int c = i >> 9, k = i & 511;
    WtOut[i] = __float2bfloat16(W_out[k * kC + c]);
  }
}

__global__ void prep_bias(const float* b_in, const float* b_pass, const float* b_tau,
                          const float* b_mem, const float* W_pass, const float* W_tau,
                          const float* W_mem, float* bias) {
  __shared__ float bp_s[kH];
  const int j = threadIdx.x;
  float s1 = 0.f, s2 = 0.f, s3 = 0.f;
  for (int k = 0; k < kH; ++k) {
    float bi = b_in[k];
    s1 += bi * W_pass[k * kH + j];
    s2 += bi * W_tau[k * kH + j];
    s3 += bi * W_mem[k * kH + j];
  }
  float bP = s1 + b_pass[j];
  bias[j]          = b_in[j];
  bias[kH + j]     = bP;
  bias[2 * kH + j] = s2 + b_tau[j];
  bias[4 * kH + j] = s3 + b_mem[j];
  bp_s[j] = bP;
  __syncthreads();
  float s4 = 0.f, s5 = 0.f;
  for (int k = 0; k < kH; ++k) {
    float v = bp_s[k];
    s4 += v * W_tau[k * kH + j];
    s5 += v * W_mem[k * kH + j];
  }
  bias[3 * kH + j] = s4 + b_tau[j];
  bias[5 * kH + j] = s5 + b_mem[j];
}

__global__ __launch_bounds__(64) void prep_mm1(const float* W_in, const __hip_bfloat16* BtP,
    const __hip_bfloat16* BtT, const __hip_bfloat16* BtM,
    __hip_bfloat16* Wall, __hip_bfloat16* Cip) {
  const int bm = blockIdx.x, bn = blockIdx.y, z = blockIdx.z;
  const int lane = threadIdx.x;
  const int kq = (lane >> 4) * 8;
  const __hip_bfloat16* Bt = (z == 0) ? BtP : (z == 1 ? BtT : BtM);
  const int mat = (z == 0) ? 1 : (z == 1 ? 2 : 4);
  const float* arow = W_in + (size_t)(bm * 16 + (lane & 15)) * kH;
  const __hip_bfloat16* brow = Bt + (size_t)(bn * 16 + (lane & 15)) * kH;
  f32x4 acc = {0.f, 0.f, 0.f, 0.f};
  for (int i = 0; i < 16; ++i) {
    const int kk = i * 32 + kq;
    acc = MFMA(ld8_f32(arow + kk), ld8(brow + kk), acc);
  }
  const int rm = (lane >> 4) * 4, cn = lane & 15;
  union { __hip_bfloat16 h[4]; ushort4 s; } cv;
#pragma unroll
  for (int r = 0; r < 4; ++r) cv.h[r] = __float2bfloat16(acc[r]);
  __hip_bfloat16* wd = Wall + ((size_t)mat * kH + bn * 16 + cn) * kKz + bm * 16 + rm;
  *(ushort4*)wd = cv.s;
  if (z == 0) {
#pragma unroll
    for (int r = 0; r < 4; ++r)
      Cip[(size_t)(bm * 16 + rm + r) * kH + bn * 16 + cn] = cv.h[r];
  }
}

__global__ __launch_bounds__(64) void prep_mm2(const __hip_bfloat16* Cip,
    const __hip_bfloat16* BtT, const __hip_bfloat16* BtM, __hip_bfloat16* Wall) {
  const int bm = blockIdx.x, bn = blockIdx.y, z = blockIdx.z;
  const int lane = threadIdx.x;
  const int kq = (lane >> 4) * 8;
  const __hip_bfloat16* Bt = (z == 0) ? BtT : BtM;
  const int mat = (z == 0) ? 3 : 5;
  const __hip_bfloat16* arow = Cip + (size_t)(bm * 16 + (lane & 15)) * kH;
  const __hip_bfloat16* brow = Bt + (size_t)(bn * 16 + (lane & 15)) * kH;
  f32x4 acc = {0.f, 0.f, 0.f, 0.f};
  for (int i = 0; i < 16; ++i) {
    const int kk = i * 32 + kq;
    acc = MFMA(ld8(arow + kk), ld8(brow + kk), acc);
  }
  const int rm = (lane >> 4) * 4, cn = lane & 15;
  union { __hip_bfloat16 h[4]; ushort4 s; } cv;
#pragma unroll
  for (int r = 0; r < 4; ++r) cv.h[r] = __float2bfloat16(acc[r]);
  __hip_bfloat16* wd = Wall + ((size_t)mat * kH + bn * 16 + cn) * kKz + bm * 16 + rm;
  *(ushort4*)wd = cv.s;
}

// ---------------- main persistent kernel ----------------

struct KParams {
  const __hip_bfloat16* xb;       // bf16 input [B][S][I]
  const __hip_bfloat16* Wall;     // [6][512][640] composites, [col][k]
  const __hip_bfloat16* WtOut;    // [64][512]
  const float* bias;              // [6][512]
  const float* b_out;             // [64]
  char* hseg;                     // [2 parity][32 slices][32 rows][16 cols] bf16
  __hip_bfloat16* h0hist;         // [64][32][512] decode-entry snapshots
  int* flag;                      // [32] per-WG publish flags, 64B stride
  int* done;                      // dummy-WG termination word
  float* scratch;                 // keep-alive sink for dummy FMA
  int* arrive;                    // tail-barrier flags
  const int* lengths;
  float* dout;                    // [B][kOutL][C]
};

__global__ __launch_bounds__(256, 1) void rnn_main(KParams P) {
  // ---- clock-boost dummies: dense FMA until real WGs finish ----
  if (blockIdx.x >= kNWG) {
    const int tid = threadIdx.x;
    float a0 = 1.0f + (float)(tid + (blockIdx.x << 8)) * 1e-6f;
    float a1 = a0 + 0.25f, a2 = a0 + 0.5f, a3 = a0 + 0.75f;
    const float m = 1.0000001f, c = 1e-7f;
    while (__hip_atomic_load(P.done, __ATOMIC_RELAXED, __HIP_MEMORY_SCOPE_AGENT) == 0) {
#pragma unroll
      for (int i = 0; i < 64; ++i) {
        a0 = __builtin_fmaf(a0, m, c);
        a1 = __builtin_fmaf(a1, m, c);
        a2 = __builtin_fmaf(a2, m, c);
        a3 = __builtin_fmaf(a3, m, c);
      }
    }
    if (a0 + a1 + a2 + a3 == 0.123456789f) *P.scratch = a0;  // never true
    return;
  }

  __shared__ float outLDS[6][kB][kJPW + 1];   // 13,056 B
  __shared__ int   len_s[kB];

  const int wg = blockIdx.x, tid = threadIdx.x;
  const int lane = tid & 63, wave = tid >> 6;
  const int q = lane >> 4, r = lane & 15;
  const int kq = q * 8;
  const int jn = wg * kJPW + r;
  const int u0m = (3 * wave) >> 1, u2m = (3 * wave + 2) >> 1;
  const __hip_bfloat16* WbA = P.Wall + ((size_t)u0m * kH + jn) * kKz;
  const __hip_bfloat16* WbC = P.Wall + ((size_t)u2m * kH + jn) * kKz;
  const bool wodd = wave & 1;
  const int eb = tid >> 3, eq = tid & 7;      // epilogue: batch, col-pair

  // A-frag base offset within a parity image: slice (q>>1), row r, col 8*(q&1)
  const unsigned baseA = (unsigned)((q >> 1) * 1024 + r * 32 + (q & 1) * 16);

  float bufr[2][kBufD];
#pragma unroll
  for (int u = 0; u < 2; ++u)
#pragma unroll
    for (int d = 0; d < kBufD; ++d) bufr[u][d] = 0.f;

  if (tid < kB) len_s[tid] = P.lengths[tid];

  for (int t = 0; t < kSteps; ++t) {
    // ---- detect: 32 lanes poll the 32 per-WG flags in parallel ----
    if (tid < kNWG) {
      const int* fp = P.flag + tid * 16;
      int f;
      do {
        f = __hip_atomic_load(fp, __ATOMIC_RELAXED, __HIP_MEMORY_SCOPE_AGENT);
      } while (!__all(f >= t));
    }
    __syncthreads();   // A: all flags >= t observed

    // ---- GEMM with A-frags loaded DIRECTLY from slice buffers ----
    const char* hbase = P.hseg + (size_t)(t & 1) * 32768;
    u32x4 A[32];
    asm volatile(
        "global_load_dwordx4 %0, %32, %40 sc0 sc1\n\t"
        "global_load_dwordx4 %1, %32, %40 offset:512 sc0 sc1\n\t"
        "global_load_dwordx4 %2, %32, %40 offset:2048 sc0 sc1\n\t"
        "global_load_dwordx4 %3, %32, %40 offset:2560 sc0 sc1\n\t"
        "global_load_dwordx4 %4, %33, %40 sc0 sc1\n\t"
        "global_load_dwordx4 %5, %33, %40 offset:512 sc0 sc1\n\t"
        "global_load_dwordx4 %6, %33, %40 offset:2048 sc0 sc1\n\t"
        "global_load_dwordx4 %7, %33, %40 offset:2560 sc0 sc1\n\t"
        "global_load_dwordx4 %8, %34, %40 sc0 sc1\n\t"
        "global_load_dwordx4 %9, %34, %40 offset:512 sc0 sc1\n\t"
        "global_load_dwordx4 %10, %34, %40 offset:2048 sc0 sc1\n\t"
        "global_load_dwordx4 %11, %34, %40 offset:2560 sc0 sc1\n\t"
        "global_load_dwordx4 %12, %35, %40 sc0 sc1\n\t"
        "global_load_dwordx4 %13, %35, %40 offset:512 sc0 sc1\n\t"
        "global_load_dwordx4 %14, %35, %40 offset:2048 sc0 sc1\n\t"
        "global_load_dwordx4 %15, %35, %40 offset:2560 sc0 sc1\n\t"
        "global_load_dwordx4 %16, %36, %40 sc0 sc1\n\t"
        "global_load_dwordx4 %17, %36, %40 offset:512 sc0 sc1\n\t"
        "global_load_dwordx4 %18, %36, %40 offset:2048 sc0 sc1\n\t"
        "global_load_dwordx4 %19, %36, %40 offset:2560 sc0 sc1\n\t"
        "global_load_dwordx4 %20, %37, %40 sc0 sc1\n\t"
        "global_load_dwordx4 %21, %37, %40 offset:512 sc0 sc1\n\t"
        "global_load_dwordx4 %22, %37, %40 offset:2048 sc0 sc1\n\t"
        "global_load_dwordx4 %23, %37, %40 offset:2560 sc0 sc1\n\t"
        "global_load_dwordx4 %24, %38, %40 sc0 sc1\n\t"
        "global_load_dwordx4 %25, %38, %40 offset:512 sc0 sc1\n\t"
        "global_load_dwordx4 %26, %38, %40 offset:2048 sc0 sc1\n\t"
        "global_load_dwordx4 %27, %38, %40 offset:2560 sc0 sc1\n\t"
        "global_load_dwordx4 %28, %39, %40 sc0 sc1\n\t"
        "global_load_dwordx4 %29, %39, %40 offset:512 sc0 sc1\n\t"
        "global_load_dwordx4 %30, %39, %40 offset:2048 sc0 sc1\n\t"
        "global_load_dwordx4 %31, %39, %40 offset:2560 sc0 sc1\n\t"
        "s_waitcnt vmcnt(0)"
        : "=&v"(A[0]), "=&v"(A[1]), "=&v"(A[2]), "=&v"(A[3]),
          "=&v"(A[4]), "=&v"(A[5]), "=&v"(A[6]), "=&v"(A[7]),
          "=&v"(A[8]), "=&v"(A[9]), "=&v"(A[10]), "=&v"(A[11]),
          "=&v"(A[12]), "=&v"(A[13]), "=&v"(A[14]), "=&v"(A[15]),
          "=&v"(A[16]), "=&v"(A[17]), "=&v"(A[18]), "=&v"(A[19]),
          "=&v"(A[20]), "=&v"(A[21]), "=&v"(A[22]), "=&v"(A[23]),
          "=&v"(A[24]), "=&v"(A[25]), "=&v"(A[26]), "=&v"(A[27]),
          "=&v"(A[28]), "=&v"(A[29]), "=&v"(A[30]), "=&v"(A[31])
        : "v"(baseA), "v"(baseA + 4096u), "v"(baseA + 8192u), "v"(baseA + 12288u),
          "v"(baseA + 16384u), "v"(baseA + 20480u), "v"(baseA + 24576u), "v"(baseA + 28672u),
          "s"(hbase)
        : "memory");

    f32x4 Acc0 = {0.f,0.f,0.f,0.f}, Acc1 = {0.f,0.f,0.f,0.f}, Acc2 = {0.f,0.f,0.f,0.f};
#pragma unroll
    for (int i = 0; i < 16; ++i) {
      const int kk = i * 32 + kq;
      const int li = 4 * (i >> 1) + (i & 1) * 2;
      bf16x8 alo = asbf(A[li]), ahi = asbf(A[li + 1]);
      bf16x8 b0 = ld8(WbA + kk), b2 = ld8(WbC + kk);
      if (!wodd) {
        Acc0 = MFMA(alo, b0, Acc0); Acc1 = MFMA(ahi, b0, Acc1); Acc2 = MFMA(alo, b2, Acc2);
      } else {
        Acc0 = MFMA(ahi, b0, Acc0); Acc1 = MFMA(alo, b2, Acc1); Acc2 = MFMA(ahi, b2, Acc2);
      }
    }
    if (t < kS) {   // x part of K (zero in decode -> skip)
#pragma unroll
      for (int i = 16; i < 20; ++i) {
        const int kk = i * 32 + kq;
        const int xo = (i - 16) * 32 + kq;
        bf16x8 alo = ld8(P.xb + ((size_t)r * kS + t) * kI + xo);
        bf16x8 ahi = ld8(P.xb + ((size_t)(r + 16) * kS + t) * kI + xo);
        bf16x8 b0 = ld8(WbA + kk), b2 = ld8(WbC + kk);
        if (!wodd) {
          Acc0 = MFMA(alo, b0, Acc0); Acc1 = MFMA(ahi, b0, Acc1); Acc2 = MFMA(alo, b2, Acc2);
        } else {
          Acc0 = MFMA(ahi, b0, Acc0); Acc1 = MFMA(alo, b2, Acc1); Acc2 = MFMA(ahi, b2, Acc2);
        }
      }
    }
    {
      f32x4 acc[3] = {Acc0, Acc1, Acc2};
#pragma unroll
      for (int s = 0; s < 3; ++s) {
        const int u = 3 * wave + s;
        const int mmat = u >> 1, rb = (u & 1) * 16;
#pragma unroll
        for (int rr = 0; rr < 4; ++rr)
          outLDS[mmat][rb + q * 4 + rr][r] = acc[s][rr];
      }
    }
    __syncthreads();   // C: outLDS ready

    // ---- epilogue 1 (critical path): gates -> front -> slice publish ----
    const bool msk = (t >= kS) || (t < len_s[eb]);
    float hv2[2], tau2[2], ml2[2];
    unsigned short bits[2];
#pragma unroll
    for (int u = 0; u < 2; ++u) {
      const int jl = eq * 2 + u, j = wg * kJPW + jl;
      float hp = outLDS[0][eb][jl] + P.bias[j];
      float pv = outLDS[1][eb][jl] + P.bias[kH + j];
      float ta = outLDS[2][eb][jl] + P.bias[2 * kH + j];
      float tb = outLDS[3][eb][jl] + P.bias[3 * kH + j];
      float ma = outLDS[4][eb][jl] + P.bias[4 * kH + j];
      float mb = outLDS[5][eb][jl] + P.bias[5 * kH + j];
      float hv = msk ? pv : hp;
      float gt = msk ? tb : ta;
      float gm = msk ? mb : ma;
      float tau = 16.f * sigm(gt);
      tau = fminf(fmaxf(tau, 1.f), 16.f);
      float ml = sigm(gm);
      hv2[u] = hv; tau2[u] = tau; ml2[u] = ml;
      float front = bufr[u][1] + (ml / (1.f + fabsf(tau - 1.f))) * hv;
      __hip_bfloat16 hb = __float2bfloat16(front);
      unsigned short bt;
      __builtin_memcpy(&bt, &hb, 2);
      bits[u] = bt;
    }
    const unsigned pk = ((unsigned)bits[1] << 16) | bits[0];
    {
      char* hw = P.hseg + (size_t)((t + 1) & 1) * 32768 + wg * 1024 + eb * 32 + eq * 4;
      __hip_atomic_store((unsigned*)hw, pk, __ATOMIC_RELAXED, __HIP_MEMORY_SCOPE_AGENT);
    }
    __builtin_amdgcn_s_waitcnt(0);   // own slice stores at coherence point
    __syncthreads();                 // D: whole WG's slice committed
    if (tid == 0)
      __hip_atomic_store(P.flag + wg * 16, t + 1,
                         __ATOMIC_RELAXED, __HIP_MEMORY_SCOPE_AGENT);

    // ---- epilogue 2 (in the shadow): buffer shift + decode snapshot ----
#pragma unroll
    for (int u = 0; u < 2; ++u) {
#pragma unroll
      for (int d = 1; d <= kMaxD; ++d) {
        float w = ml2[u] / (1.f + fabsf(tau2[u] - (float)d));
        bufr[u][d - 1] = bufr[u][d] + w * hv2[u];
      }
      bufr[u][kMaxD] = 0.f;
    }
    if ((unsigned)(t - (kS - 1)) < (unsigned)kOutL) {
      unsigned* hp = (unsigned*)(P.h0hist + ((size_t)(t - (kS - 1)) * kB + eb) * kH)
                     + (wg * 8 + eq);
      __hip_atomic_store(hp, pk, __ATOMIC_RELAXED, __HIP_MEMORY_SCOPE_AGENT);
    }
  }

  // release the clock-boost dummies
  if (tid == 0)
    __hip_atomic_store(P.done, 1, __ATOMIC_RELAXED, __HIP_MEMORY_SCOPE_AGENT);

  // ---- tail: one grid barrier over real WGs, then decode-output GEMM ----
  __builtin_amdgcn_s_waitcnt(0);
  __syncthreads();
  if (tid == 0)
    __hip_atomic_store(&P.arrive[wg * 16], 1, __ATOMIC_RELAXED, __HIP_MEMORY_SCOPE_AGENT);
  if (tid < kNWG) {
    while (__hip_atomic_load(&P.arrive[tid * 16],
                             __ATOMIC_RELAXED, __HIP_MEMORY_SCOPE_AGENT) < 1)
      __builtin_amdgcn_s_sleep(2);
  }
  __syncthreads();

  // dout[b][td][c] = h0hist[td][b][:] @ WtOut[c][:] + b_out[c]
  {
    const int mrow = wg * 64 + wave * 16 + r;   // m = td*32 + b
    const char* ap = (const char*)P.h0hist + (size_t)mrow * 1024 + q * 16;
    u32x4 d0, d1, d2, d3, d4, d5, d6, d7, d8, d9, dA, dB, dC, dD, dE, dF;
    asm volatile(
        "global_load_dwordx4 %0, %16, off sc0 sc1\n\t"
        "global_load_dwordx4 %1, %16, off offset:64 sc0 sc1\n\t"
        "global_load_dwordx4 %2, %16, off offset:128 sc0 sc1\n\t"
        "global_load_dwordx4 %3, %16, off offset:192 sc0 sc1\n\t"
        "global_load_dwordx4 %4, %16, off offset:256 sc0 sc1\n\t"
        "global_load_dwordx4 %5, %16, off offset:320 sc0 sc1\n\t"
        "global_load_dwordx4 %6, %16, off offset:384 sc0 sc1\n\t"
        "global_load_dwordx4 %7, %16, off offset:448 sc0 sc1\n\t"
        "global_load_dwordx4 %8, %16, off offset:512 sc0 sc1\n\t"
        "global_load_dwordx4 %9, %16, off offset:576 sc0 sc1\n\t"
        "global_load_dwordx4 %10, %16, off offset:640 sc0 sc1\n\t"
        "global_load_dwordx4 %11, %16, off offset:704 sc0 sc1\n\t"
        "global_load_dwordx4 %12, %16, off offset:768 sc0 sc1\n\t"
        "global_load_dwordx4 %13, %16, off offset:832 sc0 sc1\n\t"
        "global_load_dwordx4 %14, %16, off offset:896 sc0 sc1\n\t"
        "global_load_dwordx4 %15, %16, off offset:960 sc0 sc1\n\t"
        "s_waitcnt vmcnt(0)"
        : "=&v"(d0), "=&v"(d1), "=&v"(d2), "=&v"(d3),
          "=&v"(d4), "=&v"(d5), "=&v"(d6), "=&v"(d7),
          "=&v"(d8), "=&v"(d9), "=&v"(dA), "=&v"(dB),
          "=&v"(dC), "=&v"(dD), "=&v"(dE), "=&v"(dF)
        : "v"(ap)
        : "memory");
    union { u32x4 u; bf16x8 v; } av[16] = {{d0},{d1},{d2},{d3},{d4},{d5},{d6},{d7},
                                           {d8},{d9},{dA},{dB},{dC},{dD},{dE},{dF}};
    f32x4 T0 = {0.f,0.f,0.f,0.f}, T1 = {0.f,0.f,0.f,0.f};
    f32x4 T2 = {0.f,0.f,0.f,0.f}, T3 = {0.f,0.f,0.f,0.f};
#pragma unroll
    for (int ik = 0; ik < 16; ++ik) {
      const int kk = ik * 32 + kq;
      const __hip_bfloat16* wb = P.WtOut + (size_t)r * kH + kk;
      T0 = MFMA(av[ik].v, ld8(wb), T0);
      T1 = MFMA(av[ik].v, ld8(wb + 16 * kH), T1);
      T2 = MFMA(av[ik].v, ld8(wb + 32 * kH), T2);
      T3 = MFMA(av[ik].v, ld8(wb + 48 * kH), T3);
    }
    f32x4 T[4] = {T0, T1, T2, T3};
#pragma unroll
    for (int ct = 0; ct < 4; ++ct) {
      const int c = ct * 16 + r;
      const float bo = P.b_out[c];
#pragma unroll
      for (int rr = 0; rr < 4; ++rr) {
        const int m = wg * 64 + wave * 16 + q * 4 + rr;
        const int b = m & 31, td = m >> 5;
        P.dout[(size_t)b * (kOutL * kC) + td * kC + c] = T[ct][rr] + bo;
      }
    }
  }
}

extern "C" void kernel_launch(void* const* d_in, const int* in_sizes, int n_in,
                              void* d_out, int out_size, void* d_ws, size_t ws_size,
                              hipStream_t stream) {
  const float* x      = (const float*)d_in[0];
  const int*   lens   = (const int*)d_in[1];
  const float* W_in   = (const float*)d_in[3];
  const float* b_in   = (const float*)d_in[4];
  const float* W_pass = (const float*)d_in[5];
  const float* b_pass = (const float*)d_in[6];
  const float* W_tau  = (const float*)d_in[7];
  const float* b_tau  = (const float*)d_in[8];
  const float* W_mem  = (const float*)d_in[9];
  const float* b_mem  = (const float*)d_in[10];
  const float* W_out  = (const float*)d_in[11];
  const float* b_out  = (const float*)d_in[12];

  char* ws = (char*)d_ws;
  size_t off = 0;
  int* arrive = (int*)(ws + off);                  off += 2048;
  int* flag   = (int*)(ws + off);                  off += 2048;
  int* done   = (int*)(ws + off);                  off += 128;
  float* scratch = (float*)(ws + off);             off += 128;
  char* hseg  = ws + off;                          off += 65536;   // 2 x 32KB slices
  float* bias = (float*)(ws + off);                off += 6 * kH * sizeof(float);
  __hip_bfloat16* WtOut = (__hip_bfloat16*)(ws + off); off += (size_t)kC * kH * 2;
  __hip_bfloat16* h0hist = (__hip_bfloat16*)(ws + off); off += (size_t)kOutL * kB * kH * 2;
  __hip_bfloat16* xb    = (__hip_bfloat16*)(ws + off); off += (size_t)kB * kS * kI * 2;
  __hip_bfloat16* Wall  = (__hip_bfloat16*)(ws + off); off += (size_t)6 * kH * kKz * 2;
  __hip_bfloat16* BtP   = (__hip_bfloat16*)(ws + off); off += (size_t)kH * kH * 2;
  __hip_bfloat16* BtT   = (__hip_bfloat16*)(ws + off); off += (size_t)kH * kH * 2;
  __hip_bfloat16* BtM   = (__hip_bfloat16*)(ws + off); off += (size_t)kH * kH * 2;
  __hip_bfloat16* Cip   = (__hip_bfloat16*)(ws + off); off += (size_t)kKz * kH * 2;

  // zero: arrive + flags + done/scratch + both slice parities (initial h0 = 0)
  hipMemsetAsync(d_ws, 0, 2048 + 2048 + 256 + 65536, stream);

  prep_cast<<<512, 256, 0, stream>>>(x, W_in, W_pass, W_tau, W_mem, W_out,
                                     xb, Wall, BtP, BtT, BtM, WtOut);
  prep_bias<<<1, 512, 0, stream>>>(b_in, b_pass, b_tau, b_mem, W_pass, W_tau, W_mem, bias);
  prep_mm1<<<dim3(40, 32, 3), 64, 0, stream>>>(W_in, BtP, BtT, BtM, Wall, Cip);
  prep_mm2<<<dim3(40, 32, 2), 64, 0, stream>>>(Cip, BtT, BtM, Wall);

  KParams P;
  P.xb = xb; P.Wall = Wall; P.WtOut = WtOut; P.bias = bias; P.b_out = b_out;
  P.hseg = hseg; P.h0hist = h0hist; P.flag = flag; P.done = done;
  P.scratch = scratch; P.arrive = arrive; P.lengths = lens; P.dout = (float*)d_out;

  rnn_main<<<dim3(kGrid), dim3(256), 0, stream>>>(P);
}